// Round 2
// baseline (1696.799 us; speedup 1.0000x reference)
//
#include <hip/hip_runtime.h>
#include <hip/hip_bf16.h>
#include <cstdint>
#include <cstddef>

#define NP 20000
#define NA 10000
#define NEDGE 100000

// ---------- helpers ----------
__device__ __forceinline__ unsigned enc_f32(float x) {
    unsigned u = __float_as_uint(x);
    return (u & 0x80000000u) ? ~u : (u | 0x80000000u);
}
__device__ __forceinline__ float dec_f32(unsigned u) {
    u = (u & 0x80000000u) ? (u ^ 0x80000000u) : ~u;
    return __uint_as_float(u);
}

// ---------- fill ----------
__global__ __launch_bounds__(256) void fill_u32(unsigned* __restrict__ p, unsigned v, int n) {
    int i = blockIdx.x * 256 + threadIdx.x;
    if (i < n) p[i] = v;
}

// ---------- fused weight build: Weff[i, h*32+e] = sum_d W[i, h*32+d] * R[h,d,e] ----------
__global__ __launch_bounds__(256) void fuse_weights(
    const float* __restrict__ W, const float* __restrict__ b,
    const float* __restrict__ R, float* __restrict__ Weff, float* __restrict__ beff)
{
    __shared__ float wrow[256];
    const int c = threadIdx.x;
    const int h = c >> 5, e = c & 31;
    float rcol[32];
#pragma unroll
    for (int d = 0; d < 32; ++d) rcol[d] = R[(h * 32 + d) * 32 + e];
    const int i0 = blockIdx.x * 16;
    for (int ii = 0; ii < 16; ++ii) {
        const int i = i0 + ii;
        __syncthreads();
        wrow[c] = W[i * 256 + c];
        __syncthreads();
        float s = 0.f;
#pragma unroll
        for (int d = 0; d < 32; ++d) s += wrow[h * 32 + d] * rcol[d];
        Weff[i * 256 + c] = s;
    }
    if (blockIdx.x == 0) {
        __syncthreads();
        wrow[c] = b[c];
        __syncthreads();
        float s = 0.f;
#pragma unroll
        for (int d = 0; d < 32; ++d) s += wrow[h * 32 + d] * rcol[d];
        beff[c] = s;
    }
}

// ---------- generic Y[M,256] = (xscale*X[M,256]) @ W[256,256] + bias[256] ----------
__global__ __launch_bounds__(256) void gemm256(
    const float* __restrict__ X, const float* __restrict__ W,
    const float* __restrict__ bias, float* __restrict__ Y,
    int M, float xscale)
{
    __shared__ float As[64][17];
    __shared__ float Bs[16][64];
    const int tid = threadIdx.x;
    const int row0 = blockIdx.x * 64;
    const int col0 = blockIdx.y * 64;
    const int tx = tid & 15, ty = tid >> 4;
    float acc[4][4] = {};
    const int la_k = tid & 15;
    const int la_r = tid >> 4;
    const int lb_k = tid >> 6;
    const int lb_c = tid & 63;
    for (int k0 = 0; k0 < 256; k0 += 16) {
#pragma unroll
        for (int rep = 0; rep < 4; ++rep) {
            int r = la_r + 16 * rep;
            int grow = row0 + r;
            float v = 0.f;
            if (grow < M) v = X[(size_t)grow * 256 + k0 + la_k];
            As[r][la_k] = v * xscale;
        }
#pragma unroll
        for (int rep = 0; rep < 4; ++rep) {
            int kk = lb_k + 4 * rep;
            Bs[kk][lb_c] = W[(size_t)(k0 + kk) * 256 + col0 + lb_c];
        }
        __syncthreads();
#pragma unroll
        for (int kk = 0; kk < 16; ++kk) {
            float a0 = As[ty * 4 + 0][kk];
            float a1 = As[ty * 4 + 1][kk];
            float a2 = As[ty * 4 + 2][kk];
            float a3 = As[ty * 4 + 3][kk];
            const float4 b4 = *(const float4*)&Bs[kk][tx * 4];
            acc[0][0] += a0 * b4.x; acc[0][1] += a0 * b4.y; acc[0][2] += a0 * b4.z; acc[0][3] += a0 * b4.w;
            acc[1][0] += a1 * b4.x; acc[1][1] += a1 * b4.y; acc[1][2] += a1 * b4.z; acc[1][3] += a1 * b4.w;
            acc[2][0] += a2 * b4.x; acc[2][1] += a2 * b4.y; acc[2][2] += a2 * b4.z; acc[2][3] += a2 * b4.w;
            acc[3][0] += a3 * b4.x; acc[3][1] += a3 * b4.y; acc[3][2] += a3 * b4.z; acc[3][3] += a3 * b4.w;
        }
        __syncthreads();
    }
#pragma unroll
    for (int i = 0; i < 4; ++i) {
        int grow = row0 + ty * 4 + i;
        if (grow < M) {
            int gc = col0 + tx * 4;
            float4 o;
            o.x = acc[i][0] + bias[gc + 0];
            o.y = acc[i][1] + bias[gc + 1];
            o.z = acc[i][2] + bias[gc + 2];
            o.w = acc[i][3] + bias[gc + 3];
            *(float4*)&Y[(size_t)grow * 256 + gc] = o;
        }
    }
}

// ---------- edge pass 1: score + segment max ----------
__global__ __launch_bounds__(256) void edge_score(
    const float* __restrict__ Q, const float* __restrict__ K,
    const int* __restrict__ src, const int* __restrict__ dst,
    const float* __restrict__ pri, float* __restrict__ S,
    unsigned* __restrict__ MX, int E)
{
    int gid = blockIdx.x * 256 + threadIdx.x;
    int e = gid >> 3;
    if (e >= E) return;
    int h = gid & 7;
    int d = dst[e], sN = src[e];
    const float4* q = (const float4*)(Q + (size_t)d * 256 + h * 32);
    const float4* k = (const float4*)(K + (size_t)sN * 256 + h * 32);
    float s = 0.f;
#pragma unroll
    for (int j = 0; j < 8; ++j) {
        float4 a = q[j], b = k[j];
        s += a.x * b.x + a.y * b.y + a.z * b.z + a.w * b.w;
    }
    s *= pri[h] * 0.17677669529663687f;  // 1/sqrt(32)
    S[(size_t)e * 8 + h] = s;
    atomicMax(MX + (size_t)d * 8 + h, enc_f32(s));
}

// ---------- edge pass 2: exp + segment sum ----------
__global__ __launch_bounds__(256) void edge_den(
    const float* __restrict__ S, const unsigned* __restrict__ MX,
    const int* __restrict__ dst, float* __restrict__ DEN, int E)
{
    int gid = blockIdx.x * 256 + threadIdx.x;
    int e = gid >> 3;
    if (e >= E) return;
    int h = gid & 7;
    int d = dst[e];
    float m = dec_f32(MX[(size_t)d * 8 + h]);
    atomicAdd(DEN + (size_t)d * 8 + h, expf(S[(size_t)e * 8 + h] - m));
}

// ---------- edge pass 3: aggregate mu[dst] += v[src] * attn ----------
__global__ __launch_bounds__(256) void edge_aggr(
    const float* __restrict__ S, const unsigned* __restrict__ MX,
    const float* __restrict__ DEN, const float* __restrict__ V,
    const int* __restrict__ src, const int* __restrict__ dst,
    float* __restrict__ MU, int E)
{
    int gid = blockIdx.x * 256 + threadIdx.x;
    int e = gid >> 6;
    if (e >= E) return;
    int lane = gid & 63;
    int h = lane >> 3;
    int d = dst[e], sN = src[e];
    float m = dec_f32(MX[(size_t)d * 8 + h]);
    float att = expf(S[(size_t)e * 8 + h] - m) / DEN[(size_t)d * 8 + h];
    const float4 v4 = *(const float4*)(V + (size_t)sN * 256 + lane * 4);
    float* mu = MU + (size_t)d * 256 + lane * 4;
    atomicAdd(mu + 0, v4.x * att);
    atomicAdd(mu + 1, v4.y * att);
    atomicAdd(mu + 2, v4.z * att);
    atomicAdd(mu + 3, v4.w * att);
}

// ---------- skip-blend + LayerNorm ----------
__global__ __launch_bounds__(256) void out_ln(
    const float* __restrict__ O, const float* __restrict__ T,
    const float* __restrict__ skip, const float* __restrict__ lns,
    const float* __restrict__ lnb, int nt, int M, float* __restrict__ out)
{
    int gid = blockIdx.x * 256 + threadIdx.x;
    int row = gid >> 6;
    if (row >= M) return;
    int lane = gid & 63;
    float alpha = 1.f / (1.f + expf(-skip[nt]));
    float beta = 1.f - alpha;
    const float4 o4 = *(const float4*)(O + (size_t)row * 256 + lane * 4);
    const float4 t4 = *(const float4*)(T + (size_t)row * 256 + lane * 4);
    float v[4] = { o4.x * alpha + t4.x * beta, o4.y * alpha + t4.y * beta,
                   o4.z * alpha + t4.z * beta, o4.w * alpha + t4.w * beta };
    float s = v[0] + v[1] + v[2] + v[3];
#pragma unroll
    for (int mlane = 32; mlane >= 1; mlane >>= 1) s += __shfl_xor(s, mlane, 64);
    float mean = s * (1.f / 256.f);
    float sq = 0.f;
#pragma unroll
    for (int j = 0; j < 4; ++j) { float dd = v[j] - mean; sq += dd * dd; }
#pragma unroll
    for (int mlane = 32; mlane >= 1; mlane >>= 1) sq += __shfl_xor(sq, mlane, 64);
    float rstd = rsqrtf(sq * (1.f / 256.f) + 1e-5f);
    int c = lane * 4;
    const float* ls = lns + nt * 256 + c;
    const float* lb = lnb + nt * 256 + c;
    float4 r;
    r.x = (v[0] - mean) * rstd * ls[0] + lb[0];
    r.y = (v[1] - mean) * rstd * ls[1] + lb[1];
    r.z = (v[2] - mean) * rstd * ls[2] + lb[2];
    r.w = (v[3] - mean) * rstd * ls[3] + lb[3];
    *(float4*)(out + (size_t)row * 256 + c) = r;
}

extern "C" void kernel_launch(void* const* d_in, const int* in_sizes, int n_in,
                              void* d_out, int out_size, void* d_ws, size_t ws_size,
                              hipStream_t stream) {
    const float* h_paper  = (const float*)d_in[0];
    const float* h_author = (const float*)d_in[1];
    const float* t_paper  = (const float*)d_in[2];
    const float* t_author = (const float*)d_in[3];
    const float* k_w = (const float*)d_in[4];
    const float* k_b = (const float*)d_in[5];
    const float* q_w = (const float*)d_in[6];
    const float* q_b = (const float*)d_in[7];
    const float* v_w = (const float*)d_in[8];
    const float* v_b = (const float*)d_in[9];
    const float* a_w = (const float*)d_in[10];
    const float* a_b = (const float*)d_in[11];
    const float* rel_pri = (const float*)d_in[12];
    const float* rel_att = (const float*)d_in[13];
    const float* rel_msg = (const float*)d_in[14];
    const float* skip = (const float*)d_in[15];
    const float* ln_s = (const float*)d_in[16];
    const float* ln_b = (const float*)d_in[17];
    const int* src0 = (const int*)d_in[18];
    const int* dst0 = (const int*)d_in[19];
    const int* src1 = (const int*)d_in[20];
    const int* dst1 = (const int*)d_in[21];
    const int* src2 = (const int*)d_in[22];
    const int* dst2 = (const int*)d_in[23];

    float* ws = (float*)d_ws;
    // workspace layout (floats) -- no trailing backslashes in comments!
    float* Q_p  = ws + 0;          // 5,120,000
    float* Q_a  = ws + 5120000;    // 2,560,000
    float* K0   = ws + 7680000;    // 2,560,000
    float* V0   = ws + 10240000;   // 2,560,000
    float* K1   = ws + 12800000;   // 5,120,000
    float* V1   = ws + 17920000;   // 5,120,000
    float* K2   = ws + 23040000;   // 5,120,000
    float* V2   = ws + 28160000;   // 5,120,000
    float* MU_p = ws + 33280000;   // 5,120,000 (zero block start)
    float* MU_a = ws + 38400000;   // 2,560,000
    float* DEN0 = ws + 40960000;   // 160,000
    float* DEN1 = ws + 41120000;   // 160,000
    float* DEN2 = ws + 41280000;   // 80,000 (zero block end: 8,080,000 total)
    float* S0   = ws + 41360000;   // 800,000
    float* S1   = ws + 42160000;   // 800,000
    float* S2   = ws + 42960000;   // 800,000
    unsigned* MX0 = (unsigned*)(ws + 43760000);  // 160,000 (enc(-inf) block start)
    unsigned* MX1 = (unsigned*)(ws + 43920000);  // 160,000
    unsigned* MX2 = (unsigned*)(ws + 44080000);  // 80,000 (enc(-inf) block end: 400,000)
    float* WK0 = ws + 44160000 + 0 * 65536;
    float* WV0 = ws + 44160000 + 1 * 65536;
    float* WK1 = ws + 44160000 + 2 * 65536;
    float* WV1 = ws + 44160000 + 3 * 65536;
    float* WK2 = ws + 44160000 + 4 * 65536;
    float* WV2 = ws + 44160000 + 5 * 65536;
    float* BK0 = ws + 44553216 + 0 * 256;
    float* BV0 = ws + 44553216 + 1 * 256;
    float* BK1 = ws + 44553216 + 2 * 256;
    float* BV1 = ws + 44553216 + 3 * 256;
    float* BK2 = ws + 44553216 + 4 * 256;
    float* BV2 = ws + 44553216 + 5 * 256;

    // ---- init accumulators ----
    fill_u32<<<(8080000 + 255) / 256, 256, 0, stream>>>((unsigned*)MU_p, 0u, 8080000);
    fill_u32<<<(400000 + 255) / 256, 256, 0, stream>>>(MX0, 0x007FFFFFu, 400000);  // enc(-inf)

    // ---- build fused (proj x rel) weights ----
    fuse_weights<<<16, 256, 0, stream>>>(k_w + 65536, k_b + 256, rel_att + 0,     WK0, BK0);
    fuse_weights<<<16, 256, 0, stream>>>(v_w + 65536, v_b + 256, rel_msg + 0,     WV0, BV0);
    fuse_weights<<<16, 256, 0, stream>>>(k_w,         k_b,       rel_att + 8192,  WK1, BK1);
    fuse_weights<<<16, 256, 0, stream>>>(v_w,         v_b,       rel_msg + 8192,  WV1, BV1);
    fuse_weights<<<16, 256, 0, stream>>>(k_w,         k_b,       rel_att + 16384, WK2, BK2);
    fuse_weights<<<16, 256, 0, stream>>>(v_w,         v_b,       rel_msg + 16384, WV2, BV2);

    // ---- projections ----
    dim3 gP((NP + 63) / 64, 4), gA((NA + 63) / 64, 4);
    gemm256<<<gP, 256, 0, stream>>>(t_paper,  q_w,         q_b,       Q_p, NP, 1.f);
    gemm256<<<gA, 256, 0, stream>>>(t_author, q_w + 65536, q_b + 256, Q_a, NA, 1.f);
    gemm256<<<gA, 256, 0, stream>>>(h_author, WK0, BK0, K0, NA, 1.f);
    gemm256<<<gA, 256, 0, stream>>>(h_author, WV0, BV0, V0, NA, 1.f);
    gemm256<<<gP, 256, 0, stream>>>(h_paper,  WK1, BK1, K1, NP, 1.f);
    gemm256<<<gP, 256, 0, stream>>>(h_paper,  WV1, BV1, V1, NP, 1.f);
    gemm256<<<gP, 256, 0, stream>>>(h_paper,  WK2, BK2, K2, NP, 1.f);
    gemm256<<<gP, 256, 0, stream>>>(h_paper,  WV2, BV2, V2, NP, 1.f);

    // ---- edge softmax + aggregation per etype ----
    const int gE8 = (NEDGE * 8 + 255) / 256;
    const int gE64 = (NEDGE * 64 + 255) / 256;
    edge_score<<<gE8, 256, 0, stream>>>(Q_p, K0, src0, dst0, rel_pri + 0, S0, MX0, NEDGE);
    edge_den<<<gE8, 256, 0, stream>>>(S0, MX0, dst0, DEN0, NEDGE);
    edge_aggr<<<gE64, 256, 0, stream>>>(S0, MX0, DEN0, V0, src0, dst0, MU_p, NEDGE);
    edge_score<<<gE8, 256, 0, stream>>>(Q_p, K1, src1, dst1, rel_pri + 8, S1, MX1, NEDGE);
    edge_den<<<gE8, 256, 0, stream>>>(S1, MX1, dst1, DEN1, NEDGE);
    edge_aggr<<<gE64, 256, 0, stream>>>(S1, MX1, DEN1, V1, src1, dst1, MU_p, NEDGE);
    edge_score<<<gE8, 256, 0, stream>>>(Q_a, K2, src2, dst2, rel_pri + 16, S2, MX2, NEDGE);
    edge_den<<<gE8, 256, 0, stream>>>(S2, MX2, dst2, DEN2, NEDGE);
    edge_aggr<<<gE64, 256, 0, stream>>>(S2, MX2, DEN2, V2, src2, dst2, MU_a, NEDGE);

    // ---- output linear (cross-reduce mean folded into xscale for papers) ----
    float* out = (float*)d_out;
    gemm256<<<gP, 256, 0, stream>>>(MU_p, a_w,         a_b,       out,                    NP, 0.5f);
    gemm256<<<gA, 256, 0, stream>>>(MU_a, a_w + 65536, a_b + 256, out + (size_t)NP * 256, NA, 1.f);

    // ---- skip + LayerNorm (in-place) ----
    out_ln<<<(NP * 64 + 255) / 256, 256, 0, stream>>>(out, t_paper, skip, ln_s, ln_b, 0, NP, out);
    out_ln<<<(NA * 64 + 255) / 256, 256, 0, stream>>>(out + (size_t)NP * 256, t_author, skip, ln_s, ln_b, 1, NA,
                                                      out + (size_t)NP * 256);
}

// Round 3
// 775.916 us; speedup vs baseline: 2.1868x; 2.1868x over previous
//
#include <hip/hip_runtime.h>
#include <hip/hip_bf16.h>
#include <cstdint>
#include <cstddef>

#define NP 20000
#define NA 10000
#define NEDGE 100000
#define NEG_INF (-__builtin_huge_valf())

// ---------- fill ----------
__global__ __launch_bounds__(256) void fill_u32(unsigned* __restrict__ p, unsigned v, int n) {
    int i = blockIdx.x * 256 + threadIdx.x;
    if (i < n) p[i] = v;
}

// ---------- CSR build ----------
__global__ __launch_bounds__(256) void count_edges(const int* __restrict__ dst,
                                                   int* __restrict__ cnt, int E) {
    int e = blockIdx.x * 256 + threadIdx.x;
    if (e < E) atomicAdd(cnt + dst[e], 1);
}

// single block, 256 threads: exclusive scan cnt[0..n) -> rowptr[0..n]
__global__ __launch_bounds__(256) void scan_csr(const int* __restrict__ cnt,
                                                int* __restrict__ rowptr, int n) {
    __shared__ int sums[256];
    __shared__ int offs[257];
    const int t = threadIdx.x;
    const int chunk = (n + 255) / 256;
    const int lo = min(t * chunk, n), hi = min(lo + chunk, n);
    int s = 0;
    for (int i = lo; i < hi; ++i) s += cnt[i];
    sums[t] = s;
    __syncthreads();
    if (t == 0) {
        int a = 0;
        for (int i = 0; i < 256; ++i) { offs[i] = a; a += sums[i]; }
        offs[256] = a;
        rowptr[n] = a;
    }
    __syncthreads();
    int a = offs[t];
    for (int i = lo; i < hi; ++i) { rowptr[i] = a; a += cnt[i]; }
}

__global__ __launch_bounds__(256) void scatter_edges(const int* __restrict__ src,
                                                     const int* __restrict__ dst,
                                                     const int* __restrict__ rowptr,
                                                     int* __restrict__ run,
                                                     int* __restrict__ srcs, int E) {
    int e = blockIdx.x * 256 + threadIdx.x;
    if (e >= E) return;
    int d = dst[e];
    int pos = atomicAdd(run + d, 1);
    srcs[rowptr[d] + pos] = src[e];
}

// ---------- fused weight build: Weff[i, h*32+e] = sum_d W[i, h*32+d] * R[h,d,e] ----------
__global__ __launch_bounds__(256) void fuse_weights(
    const float* __restrict__ W, const float* __restrict__ b,
    const float* __restrict__ R, float* __restrict__ Weff, float* __restrict__ beff)
{
    __shared__ float wrow[256];
    const int c = threadIdx.x;
    const int h = c >> 5, e = c & 31;
    float rcol[32];
#pragma unroll
    for (int d = 0; d < 32; ++d) rcol[d] = R[(h * 32 + d) * 32 + e];
    const int i0 = blockIdx.x * 16;
    for (int ii = 0; ii < 16; ++ii) {
        const int i = i0 + ii;
        __syncthreads();
        wrow[c] = W[i * 256 + c];
        __syncthreads();
        float s = 0.f;
#pragma unroll
        for (int d = 0; d < 32; ++d) s += wrow[h * 32 + d] * rcol[d];
        Weff[i * 256 + c] = s;
    }
    if (blockIdx.x == 0) {
        __syncthreads();
        wrow[c] = b[c];
        __syncthreads();
        float s = 0.f;
#pragma unroll
        for (int d = 0; d < 32; ++d) s += wrow[h * 32 + d] * rcol[d];
        beff[c] = s;
    }
}

// ---------- generic Y[M,256] = (xscale*X[M,256]) @ W[256,256] + bias[256] ----------
__global__ __launch_bounds__(256) void gemm256(
    const float* __restrict__ X, const float* __restrict__ W,
    const float* __restrict__ bias, float* __restrict__ Y,
    int M, float xscale)
{
    __shared__ float As[64][17];
    __shared__ float Bs[16][64];
    const int tid = threadIdx.x;
    const int row0 = blockIdx.x * 64;
    const int col0 = blockIdx.y * 64;
    const int tx = tid & 15, ty = tid >> 4;
    float acc[4][4] = {};
    const int la_k = tid & 15;
    const int la_r = tid >> 4;
    const int lb_k = tid >> 6;
    const int lb_c = tid & 63;
    for (int k0 = 0; k0 < 256; k0 += 16) {
#pragma unroll
        for (int rep = 0; rep < 4; ++rep) {
            int r = la_r + 16 * rep;
            int grow = row0 + r;
            float v = 0.f;
            if (grow < M) v = X[(size_t)grow * 256 + k0 + la_k];
            As[r][la_k] = v * xscale;
        }
#pragma unroll
        for (int rep = 0; rep < 4; ++rep) {
            int kk = lb_k + 4 * rep;
            Bs[kk][lb_c] = W[(size_t)(k0 + kk) * 256 + col0 + lb_c];
        }
        __syncthreads();
#pragma unroll
        for (int kk = 0; kk < 16; ++kk) {
            float a0 = As[ty * 4 + 0][kk];
            float a1 = As[ty * 4 + 1][kk];
            float a2 = As[ty * 4 + 2][kk];
            float a3 = As[ty * 4 + 3][kk];
            const float4 b4 = *(const float4*)&Bs[kk][tx * 4];
            acc[0][0] += a0 * b4.x; acc[0][1] += a0 * b4.y; acc[0][2] += a0 * b4.z; acc[0][3] += a0 * b4.w;
            acc[1][0] += a1 * b4.x; acc[1][1] += a1 * b4.y; acc[1][2] += a1 * b4.z; acc[1][3] += a1 * b4.w;
            acc[2][0] += a2 * b4.x; acc[2][1] += a2 * b4.y; acc[2][2] += a2 * b4.z; acc[2][3] += a2 * b4.w;
            acc[3][0] += a3 * b4.x; acc[3][1] += a3 * b4.y; acc[3][2] += a3 * b4.z; acc[3][3] += a3 * b4.w;
        }
        __syncthreads();
    }
#pragma unroll
    for (int i = 0; i < 4; ++i) {
        int grow = row0 + ty * 4 + i;
        if (grow < M) {
            int gc = col0 + tx * 4;
            float4 o;
            o.x = acc[i][0] + bias[gc + 0];
            o.y = acc[i][1] + bias[gc + 1];
            o.z = acc[i][2] + bias[gc + 2];
            o.w = acc[i][3] + bias[gc + 3];
            *(float4*)&Y[(size_t)grow * 256 + gc] = o;
        }
    }
}

// ---------- per-node online-softmax aggregation, one wave per dst node ----------
// lane l: channels [l*4, l*4+4), head h = l>>3. Up to two CSR lists (papers get 2).
__device__ __forceinline__ void aggr_list(
    const float* __restrict__ K, const float* __restrict__ V,
    const int* __restrict__ rp, const int* __restrict__ srcs,
    float scaleH, int node, int lane, const float4& q, float4& accOut)
{
    const int rs = rp[node], re = rp[node + 1];
    if (rs == re) return;
    float m = NEG_INF, den = 0.f;
    float4 acc = make_float4(0.f, 0.f, 0.f, 0.f);
    int sNext = srcs[rs];
    for (int i = rs; i < re; ++i) {
        const int s = sNext;
        if (i + 1 < re) sNext = srcs[i + 1];
        const float4 k4 = *(const float4*)(K + (size_t)s * 256 + lane * 4);
        const float4 v4 = *(const float4*)(V + (size_t)s * 256 + lane * 4);
        float part = q.x * k4.x + q.y * k4.y + q.z * k4.z + q.w * k4.w;
        part += __shfl_xor(part, 1, 64);
        part += __shfl_xor(part, 2, 64);
        part += __shfl_xor(part, 4, 64);  // full head dot in all 8 lanes of group
        const float score = part * scaleH;
        const float nm = fmaxf(m, score);
        const float r = __expf(m - nm);   // m=-inf first iter -> 0
        const float p = __expf(score - nm);
        den = den * r + p;
        acc.x = acc.x * r + v4.x * p;
        acc.y = acc.y * r + v4.y * p;
        acc.z = acc.z * r + v4.z * p;
        acc.w = acc.w * r + v4.w * p;
        m = nm;
    }
    const float inv = 1.f / den;
    accOut.x += acc.x * inv;
    accOut.y += acc.y * inv;
    accOut.z += acc.z * inv;
    accOut.w += acc.w * inv;
}

__global__ __launch_bounds__(256) void node_aggr(
    const float* __restrict__ Q,
    const float* __restrict__ KA, const float* __restrict__ VA,
    const int* __restrict__ rpA, const int* __restrict__ srA,
    const float* __restrict__ KB, const float* __restrict__ VB,
    const int* __restrict__ rpB, const int* __restrict__ srB,
    const float* __restrict__ priA, const float* __restrict__ priB,
    float* __restrict__ MU, int M)
{
    int gid = blockIdx.x * 256 + threadIdx.x;
    int node = gid >> 6;
    if (node >= M) return;
    int lane = gid & 63;
    int h = lane >> 3;
    const float4 q = *(const float4*)(Q + (size_t)node * 256 + lane * 4);
    float4 acc = make_float4(0.f, 0.f, 0.f, 0.f);
    aggr_list(KA, VA, rpA, srA, priA[h] * 0.17677669529663687f, node, lane, q, acc);
    if (KB) aggr_list(KB, VB, rpB, srB, priB[h] * 0.17677669529663687f, node, lane, q, acc);
    *(float4*)(MU + (size_t)node * 256 + lane * 4) = acc;
}

// ---------- skip-blend + LayerNorm ----------
__global__ __launch_bounds__(256) void out_ln(
    const float* __restrict__ O, const float* __restrict__ T,
    const float* __restrict__ skip, const float* __restrict__ lns,
    const float* __restrict__ lnb, int nt, int M, float* __restrict__ out)
{
    int gid = blockIdx.x * 256 + threadIdx.x;
    int row = gid >> 6;
    if (row >= M) return;
    int lane = gid & 63;
    float alpha = 1.f / (1.f + expf(-skip[nt]));
    float beta = 1.f - alpha;
    const float4 o4 = *(const float4*)(O + (size_t)row * 256 + lane * 4);
    const float4 t4 = *(const float4*)(T + (size_t)row * 256 + lane * 4);
    float v[4] = { o4.x * alpha + t4.x * beta, o4.y * alpha + t4.y * beta,
                   o4.z * alpha + t4.z * beta, o4.w * alpha + t4.w * beta };
    float s = v[0] + v[1] + v[2] + v[3];
#pragma unroll
    for (int mlane = 32; mlane >= 1; mlane >>= 1) s += __shfl_xor(s, mlane, 64);
    float mean = s * (1.f / 256.f);
    float sq = 0.f;
#pragma unroll
    for (int j = 0; j < 4; ++j) { float dd = v[j] - mean; sq += dd * dd; }
#pragma unroll
    for (int mlane = 32; mlane >= 1; mlane >>= 1) sq += __shfl_xor(sq, mlane, 64);
    float rstd = rsqrtf(sq * (1.f / 256.f) + 1e-5f);
    int c = lane * 4;
    const float* ls = lns + nt * 256 + c;
    const float* lb = lnb + nt * 256 + c;
    float4 r;
    r.x = (v[0] - mean) * rstd * ls[0] + lb[0];
    r.y = (v[1] - mean) * rstd * ls[1] + lb[1];
    r.z = (v[2] - mean) * rstd * ls[2] + lb[2];
    r.w = (v[3] - mean) * rstd * ls[3] + lb[3];
    *(float4*)(out + (size_t)row * 256 + c) = r;
}

extern "C" void kernel_launch(void* const* d_in, const int* in_sizes, int n_in,
                              void* d_out, int out_size, void* d_ws, size_t ws_size,
                              hipStream_t stream) {
    const float* h_paper  = (const float*)d_in[0];
    const float* h_author = (const float*)d_in[1];
    const float* t_paper  = (const float*)d_in[2];
    const float* t_author = (const float*)d_in[3];
    const float* k_w = (const float*)d_in[4];
    const float* k_b = (const float*)d_in[5];
    const float* q_w = (const float*)d_in[6];
    const float* q_b = (const float*)d_in[7];
    const float* v_w = (const float*)d_in[8];
    const float* v_b = (const float*)d_in[9];
    const float* a_w = (const float*)d_in[10];
    const float* a_b = (const float*)d_in[11];
    const float* rel_pri = (const float*)d_in[12];
    const float* rel_att = (const float*)d_in[13];
    const float* rel_msg = (const float*)d_in[14];
    const float* skip = (const float*)d_in[15];
    const float* ln_s = (const float*)d_in[16];
    const float* ln_b = (const float*)d_in[17];
    const int* src0 = (const int*)d_in[18];
    const int* dst0 = (const int*)d_in[19];
    const int* src1 = (const int*)d_in[20];
    const int* dst1 = (const int*)d_in[21];
    const int* src2 = (const int*)d_in[22];
    const int* dst2 = (const int*)d_in[23];

    float* ws = (float*)d_ws;
    // workspace layout (floats)
    float* Q_p  = ws;                  // 5,120,000
    float* Q_a  = Q_p  + 5120000;      // 2,560,000
    float* K0   = Q_a  + 2560000;      // 2,560,000
    float* V0   = K0   + 2560000;      // 2,560,000
    float* K1   = V0   + 2560000;      // 5,120,000
    float* V1   = K1   + 5120000;      // 5,120,000
    float* K2   = V1   + 5120000;      // 5,120,000
    float* V2   = K2   + 5120000;      // 5,120,000
    float* MU_p = V2   + 5120000;      // 5,120,000 (written fully, no init needed)
    float* MU_a = MU_p + 5120000;      // 2,560,000
    float* WK0  = MU_a + 2560000;      // 6 x 65,536 fused weights
    float* WV0  = WK0 + 65536;
    float* WK1  = WV0 + 65536;
    float* WV1  = WK1 + 65536;
    float* WK2  = WV1 + 65536;
    float* WV2  = WK2 + 65536;
    float* BK0  = WV2 + 65536;         // 6 x 256 fused biases
    float* BV0  = BK0 + 256;
    float* BK1  = BV0 + 256;
    float* BV1  = BK1 + 256;
    float* BK2  = BV1 + 256;
    float* BV2  = BK2 + 256;
    // CSR area (ints)
    int* cnt0 = (int*)(BV2 + 256);     // 20,000  (zero block start)
    int* cnt1 = cnt0 + 20000;          // 20,000
    int* cnt2 = cnt1 + 20000;          // 10,000
    int* run0 = cnt2 + 10000;          // 20,000
    int* run1 = run0 + 20000;          // 20,000
    int* run2 = run1 + 20000;          // 10,000  (zero block end: 100,000 ints)
    int* rp0  = run2 + 10000;          // 20,001
    int* rp1  = rp0 + 20001;           // 20,001
    int* rp2  = rp1 + 20001;           // 10,001
    int* sr0  = rp2 + 10001;           // 100,000
    int* sr1  = sr0 + 100000;          // 100,000
    int* sr2  = sr1 + 100000;          // 100,000

    // ---- CSR build ----
    fill_u32<<<(100000 + 255) / 256, 256, 0, stream>>>((unsigned*)cnt0, 0u, 100000);
    const int gE = (NEDGE + 255) / 256;
    count_edges<<<gE, 256, 0, stream>>>(dst0, cnt0, NEDGE);
    count_edges<<<gE, 256, 0, stream>>>(dst1, cnt1, NEDGE);
    count_edges<<<gE, 256, 0, stream>>>(dst2, cnt2, NEDGE);
    scan_csr<<<1, 256, 0, stream>>>(cnt0, rp0, NP);
    scan_csr<<<1, 256, 0, stream>>>(cnt1, rp1, NP);
    scan_csr<<<1, 256, 0, stream>>>(cnt2, rp2, NA);
    scatter_edges<<<gE, 256, 0, stream>>>(src0, dst0, rp0, run0, sr0, NEDGE);
    scatter_edges<<<gE, 256, 0, stream>>>(src1, dst1, rp1, run1, sr1, NEDGE);
    scatter_edges<<<gE, 256, 0, stream>>>(src2, dst2, rp2, run2, sr2, NEDGE);

    // ---- build fused (proj x rel) weights ----
    fuse_weights<<<16, 256, 0, stream>>>(k_w + 65536, k_b + 256, rel_att + 0,     WK0, BK0);
    fuse_weights<<<16, 256, 0, stream>>>(v_w + 65536, v_b + 256, rel_msg + 0,     WV0, BV0);
    fuse_weights<<<16, 256, 0, stream>>>(k_w,         k_b,       rel_att + 8192,  WK1, BK1);
    fuse_weights<<<16, 256, 0, stream>>>(v_w,         v_b,       rel_msg + 8192,  WV1, BV1);
    fuse_weights<<<16, 256, 0, stream>>>(k_w,         k_b,       rel_att + 16384, WK2, BK2);
    fuse_weights<<<16, 256, 0, stream>>>(v_w,         v_b,       rel_msg + 16384, WV2, BV2);

    // ---- projections ----
    dim3 gP((NP + 63) / 64, 4), gA((NA + 63) / 64, 4);
    gemm256<<<gP, 256, 0, stream>>>(t_paper,  q_w,         q_b,       Q_p, NP, 1.f);
    gemm256<<<gA, 256, 0, stream>>>(t_author, q_w + 65536, q_b + 256, Q_a, NA, 1.f);
    gemm256<<<gA, 256, 0, stream>>>(h_author, WK0, BK0, K0, NA, 1.f);
    gemm256<<<gA, 256, 0, stream>>>(h_author, WV0, BV0, V0, NA, 1.f);
    gemm256<<<gP, 256, 0, stream>>>(h_paper,  WK1, BK1, K1, NP, 1.f);
    gemm256<<<gP, 256, 0, stream>>>(h_paper,  WV1, BV1, V1, NP, 1.f);
    gemm256<<<gP, 256, 0, stream>>>(h_paper,  WK2, BK2, K2, NP, 1.f);
    gemm256<<<gP, 256, 0, stream>>>(h_paper,  WV2, BV2, V2, NP, 1.f);

    // ---- per-node online softmax + aggregation (no atomics) ----
    node_aggr<<<(NP * 64 + 255) / 256, 256, 0, stream>>>(
        Q_p, K0, V0, rp0, sr0, K1, V1, rp1, sr1,
        rel_pri + 0, rel_pri + 8, MU_p, NP);
    node_aggr<<<(NA * 64 + 255) / 256, 256, 0, stream>>>(
        Q_a, K2, V2, rp2, sr2, nullptr, nullptr, nullptr, nullptr,
        rel_pri + 16, rel_pri + 16, MU_a, NA);

    // ---- output linear (cross-reduce mean folded into xscale for papers) ----
    float* out = (float*)d_out;
    gemm256<<<gP, 256, 0, stream>>>(MU_p, a_w,         a_b,       out,                    NP, 0.5f);
    gemm256<<<gA, 256, 0, stream>>>(MU_a, a_w + 65536, a_b + 256, out + (size_t)NP * 256, NA, 1.f);

    // ---- skip + LayerNorm (in-place) ----
    out_ln<<<(NP * 64 + 255) / 256, 256, 0, stream>>>(out, t_paper, skip, ln_s, ln_b, 0, NP, out);
    out_ln<<<(NA * 64 + 255) / 256, 256, 0, stream>>>(out + (size_t)NP * 256, t_author, skip, ln_s, ln_b, 1, NA,
                                                      out + (size_t)NP * 256);
}

// Round 4
// 378.564 us; speedup vs baseline: 4.4822x; 2.0496x over previous
//
#include <hip/hip_runtime.h>
#include <hip/hip_bf16.h>
#include <cstdint>
#include <cstddef>

#define NP 20000
#define NA 10000
#define NEDGE 100000
#define NEG_INF (-__builtin_huge_valf())

typedef __bf16 bf16_t;
typedef __attribute__((ext_vector_type(8))) short s16x8;
typedef __attribute__((ext_vector_type(4))) float f32x4;
typedef __attribute__((ext_vector_type(4))) __bf16 bf16x4;
typedef __attribute__((ext_vector_type(8))) __bf16 bf16x8v;

union B16 { uint4 u; s16x8 s; bf16x8v b; };

// ---------- fill ----------
__global__ __launch_bounds__(256) void fill_u32(unsigned* __restrict__ p, unsigned v, int n) {
    int i = blockIdx.x * 256 + threadIdx.x;
    if (i < n) p[i] = v;
}

// ---------- fp32 -> bf16 (with scale), n multiple of 8 ----------
__global__ __launch_bounds__(256) void f2b(const float* __restrict__ in, bf16_t* __restrict__ out,
                                           int n, float scale) {
    int i = blockIdx.x * 256 + threadIdx.x;
    int idx = i * 8;
    if (idx >= n) return;
    float4 a = *(const float4*)(in + idx);
    float4 b = *(const float4*)(in + idx + 4);
    B16 o;
    o.b[0] = (__bf16)(a.x * scale); o.b[1] = (__bf16)(a.y * scale);
    o.b[2] = (__bf16)(a.z * scale); o.b[3] = (__bf16)(a.w * scale);
    o.b[4] = (__bf16)(b.x * scale); o.b[5] = (__bf16)(b.y * scale);
    o.b[6] = (__bf16)(b.z * scale); o.b[7] = (__bf16)(b.w * scale);
    *(uint4*)(out + idx) = o.u;
}

// ---------- CSR build ----------
__global__ __launch_bounds__(256) void count_edges(const int* __restrict__ dst,
                                                   int* __restrict__ cnt, int E) {
    int e = blockIdx.x * 256 + threadIdx.x;
    if (e < E) atomicAdd(cnt + dst[e], 1);
}

__global__ __launch_bounds__(256) void scan_csr(const int* __restrict__ cnt,
                                                int* __restrict__ rowptr, int n) {
    __shared__ int sums[256];
    __shared__ int offs[257];
    const int t = threadIdx.x;
    const int chunk = (n + 255) / 256;
    const int lo = min(t * chunk, n), hi = min(lo + chunk, n);
    int s = 0;
    for (int i = lo; i < hi; ++i) s += cnt[i];
    sums[t] = s;
    __syncthreads();
    if (t == 0) {
        int a = 0;
        for (int i = 0; i < 256; ++i) { offs[i] = a; a += sums[i]; }
        offs[256] = a;
        rowptr[n] = a;
    }
    __syncthreads();
    int a = offs[t];
    for (int i = lo; i < hi; ++i) { rowptr[i] = a; a += cnt[i]; }
}

__global__ __launch_bounds__(256) void scatter_edges(const int* __restrict__ src,
                                                     const int* __restrict__ dst,
                                                     const int* __restrict__ rowptr,
                                                     int* __restrict__ run,
                                                     int* __restrict__ srcs, int E) {
    int e = blockIdx.x * 256 + threadIdx.x;
    if (e >= E) return;
    int d = dst[e];
    int pos = atomicAdd(run + d, 1);
    srcs[rowptr[d] + pos] = src[e];
}

// ---------- fused weight build, TRANSPOSED bf16 output ----------
// WT[c][i] = bf16( sum_d W[i, h*32+d] * R[h,d,e] ),  c = h*32+e; beff[c] likewise from b.
__global__ __launch_bounds__(256) void fuse_w_t(
    const float* __restrict__ W, const float* __restrict__ b,
    const float* __restrict__ R, bf16_t* __restrict__ WT, float* __restrict__ beff)
{
    __shared__ float rs[32];
    const int c = blockIdx.x;
    const int h = c >> 5, e = c & 31;
    const int t = threadIdx.x;
    if (t < 32) rs[t] = R[(h * 32 + t) * 32 + e];
    __syncthreads();
    float s = 0.f;
#pragma unroll
    for (int d = 0; d < 32; ++d) s += W[t * 256 + h * 32 + d] * rs[d];
    WT[c * 256 + t] = (bf16_t)s;
    if (t == 0) {
        float sb = 0.f;
#pragma unroll
        for (int d = 0; d < 32; ++d) sb += b[h * 32 + d] * rs[d];
        beff[c] = sb;
    }
}

// ---------- plain transpose W[256][256] -> WT bf16 ----------
__global__ __launch_bounds__(256) void transp_w(const float* __restrict__ W, bf16_t* __restrict__ WT) {
    const int c = blockIdx.x, t = threadIdx.x;
    WT[c * 256 + t] = (bf16_t)W[t * 256 + c];
}

// ---------- bf16 MFMA GEMM: Y[M,ldY] = X[M,256] @ WT^T + bias ----------
// X row-major bf16 [M][256]; WT row-major bf16 [N][256] (i.e., B transposed).
// 256 threads = 4 waves in 2x2; BM=BN=128, BK=32. LDS slot-swizzled, linear layout.
template<int OUT_BF16>
__global__ __launch_bounds__(256) void gemm_mfma(
    const bf16_t* __restrict__ X, const bf16_t* __restrict__ WT,
    const float* __restrict__ bias, float* __restrict__ Yf, bf16_t* __restrict__ Yb,
    int M, int ldY)
{
    __shared__ uint4 As4[512];  // [row 128][slot 4], slot XOR-swizzled by (row>>1)&3
    __shared__ uint4 Bs4[512];
    const int t = threadIdx.x;
    const int row0 = blockIdx.x * 128;
    const int col0 = blockIdx.y * 128;
    const int w = t >> 6, l = t & 63;
    const int wm = w >> 1, wn = w & 1;
    f32x4 acc[4][4] = {};
    const int lr = l & 15, ks = l >> 4;
    for (int k0 = 0; k0 < 256; k0 += 32) {
#pragma unroll
        for (int j = 0; j < 2; ++j) {
            const int c = t + 256 * j;
            const int r = c >> 2, s = c & 3;
            const int sp = s ^ ((r >> 1) & 3);
            const int gr = row0 + r;
            uint4 va;
            if (gr < M) va = *(const uint4*)(X + (size_t)gr * 256 + k0 + s * 8);
            else { va.x = va.y = va.z = va.w = 0u; }
            As4[r * 4 + sp] = va;
            Bs4[r * 4 + sp] = *(const uint4*)(WT + (size_t)(col0 + r) * 256 + k0 + s * 8);
        }
        __syncthreads();
        B16 af[4], bfr[4];
#pragma unroll
        for (int i = 0; i < 4; ++i) {
            const int ra = wm * 64 + i * 16 + lr;
            af[i].u = As4[ra * 4 + (ks ^ ((ra >> 1) & 3))];
            const int rb = wn * 64 + i * 16 + lr;
            bfr[i].u = Bs4[rb * 4 + (ks ^ ((rb >> 1) & 3))];
        }
#pragma unroll
        for (int i = 0; i < 4; ++i)
#pragma unroll
            for (int jn = 0; jn < 4; ++jn)
                acc[i][jn] = __builtin_amdgcn_mfma_f32_16x16x32_bf16(af[i].s, bfr[jn].s, acc[i][jn], 0, 0, 0);
        __syncthreads();
    }
    const int lq = l >> 4;
#pragma unroll
    for (int i = 0; i < 4; ++i) {
        const int rbase = row0 + wm * 64 + i * 16 + lq * 4;
#pragma unroll
        for (int jn = 0; jn < 4; ++jn) {
            const int col = col0 + wn * 64 + jn * 16 + lr;
            const float bv = bias[col];
#pragma unroll
            for (int r = 0; r < 4; ++r) {
                const int grow = rbase + r;
                if (grow < M) {
                    const float v = acc[i][jn][r] + bv;
                    if (OUT_BF16) Yb[(size_t)grow * ldY + col] = (bf16_t)v;
                    else          Yf[(size_t)grow * ldY + col] = v;
                }
            }
        }
    }
}

// ---------- per-node online-softmax aggregation (bf16 Q/K/V, fp32 math) ----------
__device__ __forceinline__ float4 ldb4(const bf16_t* p) {
    bf16x4 v = *(const bf16x4*)p;
    return make_float4((float)v[0], (float)v[1], (float)v[2], (float)v[3]);
}

__device__ __forceinline__ void aggr_list(
    const bf16_t* __restrict__ K, const bf16_t* __restrict__ V, int ld,
    const int* __restrict__ rp, const int* __restrict__ srcs,
    float scaleH, int node, int lane, const float4& q, float4& accOut)
{
    const int rs = rp[node], re = rp[node + 1];
    if (rs == re) return;
    float m = NEG_INF, den = 0.f;
    float4 acc = make_float4(0.f, 0.f, 0.f, 0.f);
    int sNext = srcs[rs];
    for (int i = rs; i < re; ++i) {
        const int s = sNext;
        if (i + 1 < re) sNext = srcs[i + 1];
        const float4 k4 = ldb4(K + (size_t)s * ld + lane * 4);
        const float4 v4 = ldb4(V + (size_t)s * ld + lane * 4);
        float part = q.x * k4.x + q.y * k4.y + q.z * k4.z + q.w * k4.w;
        part += __shfl_xor(part, 1, 64);
        part += __shfl_xor(part, 2, 64);
        part += __shfl_xor(part, 4, 64);
        const float score = part * scaleH;
        const float nm = fmaxf(m, score);
        const float r = __expf(m - nm);
        const float p = __expf(score - nm);
        den = den * r + p;
        acc.x = acc.x * r + v4.x * p;
        acc.y = acc.y * r + v4.y * p;
        acc.z = acc.z * r + v4.z * p;
        acc.w = acc.w * r + v4.w * p;
        m = nm;
    }
    const float inv = 1.f / den;
    accOut.x += acc.x * inv;
    accOut.y += acc.y * inv;
    accOut.z += acc.z * inv;
    accOut.w += acc.w * inv;
}

__global__ __launch_bounds__(256) void node_aggr(
    const bf16_t* __restrict__ Q,
    const bf16_t* __restrict__ KA, const bf16_t* __restrict__ VA, int ldA,
    const int* __restrict__ rpA, const int* __restrict__ srA,
    const bf16_t* __restrict__ KB, const bf16_t* __restrict__ VB, int ldB,
    const int* __restrict__ rpB, const int* __restrict__ srB,
    const float* __restrict__ priA, const float* __restrict__ priB,
    float* __restrict__ MU, int M)
{
    int gid = blockIdx.x * 256 + threadIdx.x;
    int node = gid >> 6;
    if (node >= M) return;
    int lane = gid & 63;
    int h = lane >> 3;
    const float4 q = ldb4(Q + (size_t)node * 256 + lane * 4);
    float4 acc = make_float4(0.f, 0.f, 0.f, 0.f);
    aggr_list(KA, VA, ldA, rpA, srA, priA[h] * 0.17677669529663687f, node, lane, q, acc);
    if (KB) aggr_list(KB, VB, ldB, rpB, srB, priB[h] * 0.17677669529663687f, node, lane, q, acc);
    *(float4*)(MU + (size_t)node * 256 + lane * 4) = acc;
}

// ---------- skip-blend + LayerNorm ----------
__global__ __launch_bounds__(256) void out_ln(
    const float* __restrict__ O, const float* __restrict__ T,
    const float* __restrict__ skip, const float* __restrict__ lns,
    const float* __restrict__ lnb, int nt, int M, float* __restrict__ out)
{
    int gid = blockIdx.x * 256 + threadIdx.x;
    int row = gid >> 6;
    if (row >= M) return;
    int lane = gid & 63;
    float alpha = 1.f / (1.f + expf(-skip[nt]));
    float beta = 1.f - alpha;
    const float4 o4 = *(const float4*)(O + (size_t)row * 256 + lane * 4);
    const float4 t4 = *(const float4*)(T + (size_t)row * 256 + lane * 4);
    float v[4] = { o4.x * alpha + t4.x * beta, o4.y * alpha + t4.y * beta,
                   o4.z * alpha + t4.z * beta, o4.w * alpha + t4.w * beta };
    float s = v[0] + v[1] + v[2] + v[3];
#pragma unroll
    for (int mlane = 32; mlane >= 1; mlane >>= 1) s += __shfl_xor(s, mlane, 64);
    float mean = s * (1.f / 256.f);
    float sq = 0.f;
#pragma unroll
    for (int j = 0; j < 4; ++j) { float dd = v[j] - mean; sq += dd * dd; }
#pragma unroll
    for (int mlane = 32; mlane >= 1; mlane >>= 1) sq += __shfl_xor(sq, mlane, 64);
    float rstd = rsqrtf(sq * (1.f / 256.f) + 1e-5f);
    int c = lane * 4;
    const float* ls = lns + nt * 256 + c;
    const float* lb = lnb + nt * 256 + c;
    float4 r;
    r.x = (v[0] - mean) * rstd * ls[0] + lb[0];
    r.y = (v[1] - mean) * rstd * ls[1] + lb[1];
    r.z = (v[2] - mean) * rstd * ls[2] + lb[2];
    r.w = (v[3] - mean) * rstd * ls[3] + lb[3];
    *(float4*)(out + (size_t)row * 256 + c) = r;
}

extern "C" void kernel_launch(void* const* d_in, const int* in_sizes, int n_in,
                              void* d_out, int out_size, void* d_ws, size_t ws_size,
                              hipStream_t stream) {
    const float* h_paper  = (const float*)d_in[0];
    const float* h_author = (const float*)d_in[1];
    const float* t_paper  = (const float*)d_in[2];
    const float* t_author = (const float*)d_in[3];
    const float* k_w = (const float*)d_in[4];
    const float* k_b = (const float*)d_in[5];
    const float* q_w = (const float*)d_in[6];
    const float* q_b = (const float*)d_in[7];
    const float* v_w = (const float*)d_in[8];
    const float* v_b = (const float*)d_in[9];
    const float* a_w = (const float*)d_in[10];
    const float* a_b = (const float*)d_in[11];
    const float* rel_pri = (const float*)d_in[12];
    const float* rel_att = (const float*)d_in[13];
    const float* rel_msg = (const float*)d_in[14];
    const float* skip = (const float*)d_in[15];
    const float* ln_s = (const float*)d_in[16];
    const float* ln_b = (const float*)d_in[17];
    const int* src0 = (const int*)d_in[18];
    const int* dst0 = (const int*)d_in[19];
    const int* src1 = (const int*)d_in[20];
    const int* dst1 = (const int*)d_in[21];
    const int* src2 = (const int*)d_in[22];
    const int* dst2 = (const int*)d_in[23];

    // ---- workspace layout (bytes, 256B-aligned blocks) ----
    char* base = (char*)d_ws;
    size_t off = 0;
    auto alloc = [&](size_t bytes) { char* p = base + off; off += (bytes + 255) & ~(size_t)255; return p; };
    bf16_t* Xhp = (bf16_t*)alloc((size_t)NP * 256 * 2);
    bf16_t* Xha = (bf16_t*)alloc((size_t)NA * 256 * 2);
    bf16_t* Xtp = (bf16_t*)alloc((size_t)NP * 256 * 2);
    bf16_t* Xta = (bf16_t*)alloc((size_t)NA * 256 * 2);
    bf16_t* Yhp = (bf16_t*)alloc((size_t)NP * 1024 * 2);  // K1|V1|K2|V2
    bf16_t* Yha = (bf16_t*)alloc((size_t)NA * 512 * 2);   // K0|V0
    bf16_t* Qp  = (bf16_t*)alloc((size_t)NP * 256 * 2);
    bf16_t* Qa  = (bf16_t*)alloc((size_t)NA * 256 * 2);
    float*  MUp = (float*)alloc((size_t)NP * 256 * 4);
    float*  MUa = (float*)alloc((size_t)NA * 256 * 4);
    bf16_t* MUpb = (bf16_t*)alloc((size_t)NP * 256 * 2);
    bf16_t* MUab = (bf16_t*)alloc((size_t)NA * 256 * 2);
    bf16_t* WT_hp = (bf16_t*)alloc(1024 * 256 * 2);
    bf16_t* WT_ha = (bf16_t*)alloc(512 * 256 * 2);
    bf16_t* WT_q0 = (bf16_t*)alloc(256 * 256 * 2);
    bf16_t* WT_q1 = (bf16_t*)alloc(256 * 256 * 2);
    bf16_t* WT_a0 = (bf16_t*)alloc(256 * 256 * 2);
    bf16_t* WT_a1 = (bf16_t*)alloc(256 * 256 * 2);
    float* Bhp = (float*)alloc(1024 * 4);
    float* Bha = (float*)alloc(512 * 4);
    int* cnt0 = (int*)alloc(5 * 20000 * 4 + 10000 * 4 * 0);  // cnt0,cnt1,cnt2,run0,run1,run2 = 100000 ints
    int* cnt1 = cnt0 + 20000;
    int* cnt2 = cnt1 + 20000;
    int* run0 = cnt2 + 10000;
    int* run1 = run0 + 20000;
    int* run2 = run1 + 20000;
    (void)alloc(0);  // cnt block already sized: 5*20000*4 = 400000 bytes covers 100000 ints
    int* rp0 = (int*)alloc(20001 * 4);
    int* rp1 = (int*)alloc(20001 * 4);
    int* rp2 = (int*)alloc(10001 * 4);
    int* sr0 = (int*)alloc(100000 * 4);
    int* sr1 = (int*)alloc(100000 * 4);
    int* sr2 = (int*)alloc(100000 * 4);

    // ---- CSR build ----
    fill_u32<<<(100000 + 255) / 256, 256, 0, stream>>>((unsigned*)cnt0, 0u, 100000);
    const int gE = (NEDGE + 255) / 256;
    count_edges<<<gE, 256, 0, stream>>>(dst0, cnt0, NEDGE);
    count_edges<<<gE, 256, 0, stream>>>(dst1, cnt1, NEDGE);
    count_edges<<<gE, 256, 0, stream>>>(dst2, cnt2, NEDGE);
    scan_csr<<<1, 256, 0, stream>>>(cnt0, rp0, NP);
    scan_csr<<<1, 256, 0, stream>>>(cnt1, rp1, NP);
    scan_csr<<<1, 256, 0, stream>>>(cnt2, rp2, NA);
    scatter_edges<<<gE, 256, 0, stream>>>(src0, dst0, rp0, run0, sr0, NEDGE);
    scatter_edges<<<gE, 256, 0, stream>>>(src1, dst1, rp1, run1, sr1, NEDGE);
    scatter_edges<<<gE, 256, 0, stream>>>(src2, dst2, rp2, run2, sr2, NEDGE);

    // ---- activations -> bf16 ----
    const int nP8 = NP * 256 / 8, nA8 = NA * 256 / 8;
    f2b<<<(nP8 + 255) / 256, 256, 0, stream>>>(h_paper,  Xhp, NP * 256, 1.f);
    f2b<<<(nA8 + 255) / 256, 256, 0, stream>>>(h_author, Xha, NA * 256, 1.f);
    f2b<<<(nP8 + 255) / 256, 256, 0, stream>>>(t_paper,  Xtp, NP * 256, 1.f);
    f2b<<<(nA8 + 255) / 256, 256, 0, stream>>>(t_author, Xta, NA * 256, 1.f);

    // ---- weights: fused (proj x rel), transposed bf16 ----
    // Yhp columns: [K1 | V1 | K2 | V2]  (src = paper, nt 0)
    fuse_w_t<<<256, 256, 0, stream>>>(k_w,         k_b,       rel_att + 8192,  WT_hp + 0 * 65536, Bhp + 0);
    fuse_w_t<<<256, 256, 0, stream>>>(v_w,         v_b,       rel_msg + 8192,  WT_hp + 1 * 65536, Bhp + 256);
    fuse_w_t<<<256, 256, 0, stream>>>(k_w,         k_b,       rel_att + 16384, WT_hp + 2 * 65536, Bhp + 512);
    fuse_w_t<<<256, 256, 0, stream>>>(v_w,         v_b,       rel_msg + 16384, WT_hp + 3 * 65536, Bhp + 768);
    // Yha columns: [K0 | V0]  (src = author, nt 1)
    fuse_w_t<<<256, 256, 0, stream>>>(k_w + 65536, k_b + 256, rel_att + 0,     WT_ha + 0 * 65536, Bha + 0);
    fuse_w_t<<<256, 256, 0, stream>>>(v_w + 65536, v_b + 256, rel_msg + 0,     WT_ha + 1 * 65536, Bha + 256);
    transp_w<<<256, 256, 0, stream>>>(q_w,         WT_q0);
    transp_w<<<256, 256, 0, stream>>>(q_w + 65536, WT_q1);
    transp_w<<<256, 256, 0, stream>>>(a_w,         WT_a0);
    transp_w<<<256, 256, 0, stream>>>(a_w + 65536, WT_a1);

    // ---- MFMA projections (bf16 out) ----
    gemm_mfma<1><<<dim3(157, 8), 256, 0, stream>>>(Xhp, WT_hp, Bhp, nullptr, Yhp, NP, 1024);
    gemm_mfma<1><<<dim3(79, 4),  256, 0, stream>>>(Xha, WT_ha, Bha, nullptr, Yha, NA, 512);
    gemm_mfma<1><<<dim3(157, 2), 256, 0, stream>>>(Xtp, WT_q0, q_b,       nullptr, Qp, NP, 256);
    gemm_mfma<1><<<dim3(79, 2),  256, 0, stream>>>(Xta, WT_q1, q_b + 256, nullptr, Qa, NA, 256);

    // ---- per-node online softmax + aggregation ----
    node_aggr<<<(NP * 64 + 255) / 256, 256, 0, stream>>>(
        Qp, Yha + 0, Yha + 256, 512, rp0, sr0,
        Yhp + 0, Yhp + 256, 1024, rp1, sr1,
        rel_pri + 0, rel_pri + 8, MUp, NP);
    node_aggr<<<(NA * 64 + 255) / 256, 256, 0, stream>>>(
        Qa, Yhp + 512, Yhp + 768, 1024, rp2, sr2,
        (const bf16_t*)nullptr, (const bf16_t*)nullptr, 0, nullptr, nullptr,
        rel_pri + 16, rel_pri + 16, MUa, NA);

    // ---- MU -> bf16 (0.5 cross-reduce folded for papers) ----
    f2b<<<(nP8 + 255) / 256, 256, 0, stream>>>(MUp, MUpb, NP * 256, 0.5f);
    f2b<<<(nA8 + 255) / 256, 256, 0, stream>>>(MUa, MUab, NA * 256, 1.f);

    // ---- output linear (fp32 out) ----
    float* out = (float*)d_out;
    gemm_mfma<0><<<dim3(157, 2), 256, 0, stream>>>(MUpb, WT_a0, a_b,       out,                    nullptr, NP, 256);
    gemm_mfma<0><<<dim3(79, 2),  256, 0, stream>>>(MUab, WT_a1, a_b + 256, out + (size_t)NP * 256, nullptr, NA, 256);

    // ---- skip + LayerNorm (in-place) ----
    out_ln<<<(NP * 64 + 255) / 256, 256, 0, stream>>>(out, t_paper, skip, ln_s, ln_b, 0, NP, out);
    out_ln<<<(NA * 64 + 255) / 256, 256, 0, stream>>>(out + (size_t)NP * 256, t_author, skip, ln_s, ln_b, 1, NA,
                                                      out + (size_t)NP * 256);
}

// Round 6
// 238.613 us; speedup vs baseline: 7.1111x; 1.5865x over previous
//
#include <hip/hip_runtime.h>
#include <hip/hip_bf16.h>
#include <cstdint>
#include <cstddef>

#define NP 20000
#define NA 10000
#define NEDGE 100000
#define NEG_INF (-__builtin_huge_valf())
#define INV_SQRT_DK 0.17677669529663687f

typedef __bf16 bf16_t;
typedef __attribute__((ext_vector_type(8))) short s16x8;
typedef __attribute__((ext_vector_type(4))) float f32x4;
typedef __attribute__((ext_vector_type(4))) __bf16 bf16x4;
typedef __attribute__((ext_vector_type(8))) __bf16 bf16x8v;

union B16 { uint4 u; s16x8 s; bf16x8v b; };

// ---------- fill ----------
__global__ __launch_bounds__(256) void fill_u32(unsigned* __restrict__ p, unsigned v, int n) {
    int i = blockIdx.x * 256 + threadIdx.x;
    if (i < n) p[i] = v;
}

// ---------- CSR build (3 etypes per launch) ----------
__global__ __launch_bounds__(256) void count3(
    const int* __restrict__ d0, const int* __restrict__ d1, const int* __restrict__ d2,
    int* __restrict__ c0, int* __restrict__ c1, int* __restrict__ c2, int E)
{
    int e = blockIdx.x * 256 + threadIdx.x;
    if (e >= E) return;
    const int* d; int* c;
    switch (blockIdx.y) { case 0: d = d0; c = c0; break; case 1: d = d1; c = c1; break; default: d = d2; c = c2; }
    atomicAdd(c + d[e], 1);
}

__global__ __launch_bounds__(256) void scan3(
    const int* __restrict__ c0, const int* __restrict__ c1, const int* __restrict__ c2,
    int* __restrict__ r0, int* __restrict__ r1, int* __restrict__ r2)
{
    const int* cnt; int* rp; int n;
    switch (blockIdx.x) { case 0: cnt = c0; rp = r0; n = NP; break;
                          case 1: cnt = c1; rp = r1; n = NP; break;
                          default: cnt = c2; rp = r2; n = NA; }
    __shared__ int sums[256];
    __shared__ int offs[257];
    const int t = threadIdx.x;
    const int chunk = (n + 255) / 256;
    const int lo = min(t * chunk, n), hi = min(lo + chunk, n);
    int s = 0;
    for (int i = lo; i < hi; ++i) s += cnt[i];
    sums[t] = s;
    __syncthreads();
    if (t == 0) {
        int a = 0;
        for (int i = 0; i < 256; ++i) { offs[i] = a; a += sums[i]; }
        rp[n] = a;
    }
    __syncthreads();
    int a = offs[t];
    for (int i = lo; i < hi; ++i) { rp[i] = a; a += cnt[i]; }
}

__global__ __launch_bounds__(256) void scatter3(
    const int* __restrict__ s0, const int* __restrict__ d0,
    const int* __restrict__ s1, const int* __restrict__ d1,
    const int* __restrict__ s2, const int* __restrict__ d2,
    const int* __restrict__ r0, const int* __restrict__ r1, const int* __restrict__ r2,
    int* __restrict__ run0, int* __restrict__ run1, int* __restrict__ run2,
    int* __restrict__ sr0, int* __restrict__ sr1, int* __restrict__ sr2, int E)
{
    int e = blockIdx.x * 256 + threadIdx.x;
    if (e >= E) return;
    const int *src, *dst, *rp; int *run, *srs;
    switch (blockIdx.y) {
        case 0: src = s0; dst = d0; rp = r0; run = run0; srs = sr0; break;
        case 1: src = s1; dst = d1; rp = r1; run = run1; srs = sr1; break;
        default: src = s2; dst = d2; rp = r2; run = run2; srs = sr2;
    }
    int d = dst[e];
    int pos = atomicAdd(run + d, 1);
    srs[rp[d] + pos] = src[e];
}

// ---------- weight prep: 6 fused (proj x rel) + 4 plain transposes, all bf16 transposed ----------
__global__ __launch_bounds__(256) void prep_weights(
    const float* __restrict__ k_w, const float* __restrict__ k_b,
    const float* __restrict__ v_w, const float* __restrict__ v_b,
    const float* __restrict__ q_w, const float* __restrict__ a_w,
    const float* __restrict__ rel_att, const float* __restrict__ rel_msg,
    bf16_t* __restrict__ WT_hp, float* __restrict__ Bhp,
    bf16_t* __restrict__ WT_ha, float* __restrict__ Bha,
    bf16_t* __restrict__ WT_q0, bf16_t* __restrict__ WT_q1,
    bf16_t* __restrict__ WT_a0, bf16_t* __restrict__ WT_a1)
{
    const int y = blockIdx.y;
    const int c = blockIdx.x;
    const int t = threadIdx.x;
    if (y < 6) {
        const float *W, *b, *R; bf16_t* WT; float* bias;
        switch (y) {
            case 0: W = k_w;         b = k_b;       R = rel_att + 8192;  WT = WT_hp;          bias = Bhp;       break;
            case 1: W = v_w;         b = v_b;       R = rel_msg + 8192;  WT = WT_hp + 65536;  bias = Bhp + 256; break;
            case 2: W = k_w;         b = k_b;       R = rel_att + 16384; WT = WT_hp + 131072; bias = Bhp + 512; break;
            case 3: W = v_w;         b = v_b;       R = rel_msg + 16384; WT = WT_hp + 196608; bias = Bhp + 768; break;
            case 4: W = k_w + 65536; b = k_b + 256; R = rel_att;         WT = WT_ha;          bias = Bha;       break;
            default:W = v_w + 65536; b = v_b + 256; R = rel_msg;         WT = WT_ha + 65536;  bias = Bha + 256;
        }
        __shared__ float rs[32];
        const int h = c >> 5, e = c & 31;
        if (t < 32) rs[t] = R[(h * 32 + t) * 32 + e];
        __syncthreads();
        float s = 0.f;
#pragma unroll
        for (int d = 0; d < 32; ++d) s += W[t * 256 + h * 32 + d] * rs[d];
        WT[c * 256 + t] = (bf16_t)s;
        if (t == 0) {
            float sb = 0.f;
#pragma unroll
            for (int d = 0; d < 32; ++d) sb += b[h * 32 + d] * rs[d];
            bias[c] = sb;
        }
    } else {
        const float* W; bf16_t* WT;
        switch (y) { case 6: W = q_w; WT = WT_q0; break;
                     case 7: W = q_w + 65536; WT = WT_q1; break;
                     case 8: W = a_w; WT = WT_a0; break;
                     default: W = a_w + 65536; WT = WT_a1; }
        WT[c * 256 + t] = (bf16_t)W[t * 256 + c];
    }
}

// ---------- bf16 MFMA GEMM, fp32 OR bf16 X input, two row segments ----------
// Y[M,ldY] = X[M,256] @ WT^T + bias.  WT row-major bf16 [N][256].
template<int IN_BF16, int OUT_BF16>
__global__ __launch_bounds__(256) void gemm_mfma(
    const void* __restrict__ Xa, const bf16_t* __restrict__ WTa, const float* __restrict__ biasa,
    void* __restrict__ Ya, int Ma, int nblkA, int ldYa,
    const void* __restrict__ Xb, const bf16_t* __restrict__ WTb, const float* __restrict__ biasb,
    void* __restrict__ Yb, int Mb, int ldYb)
{
    int bx = blockIdx.x;
    const void* X; const bf16_t* WT; const float* bias; int M, ldY; void* Yv;
    if (bx < nblkA) { X = Xa; WT = WTa; bias = biasa; M = Ma; ldY = ldYa; Yv = Ya; }
    else { bx -= nblkA; X = Xb; WT = WTb; bias = biasb; M = Mb; ldY = ldYb; Yv = Yb; }
    const int col0 = blockIdx.y * 128;
    if (col0 >= ldY) return;
    const int row0 = bx * 128;

    __shared__ uint4 As4[512];  // [row 128][slot 4], slot XOR-swizzled by (row>>1)&3
    __shared__ uint4 Bs4[512];
    const int t = threadIdx.x;
    const int w = t >> 6, l = t & 63;
    const int wm = w >> 1, wn = w & 1;
    f32x4 acc[4][4] = {};
    const int lr = l & 15, ks = l >> 4;
    for (int k0 = 0; k0 < 256; k0 += 32) {
#pragma unroll
        for (int j = 0; j < 2; ++j) {
            const int c = t + 256 * j;
            const int r = c >> 2, s = c & 3;
            const int sp = s ^ ((r >> 1) & 3);
            const int gr = row0 + r;
            uint4 va;
            if (gr < M) {
                if (IN_BF16) {
                    va = *(const uint4*)((const bf16_t*)X + (size_t)gr * 256 + k0 + s * 8);
                } else {
                    const float* xp = (const float*)X + (size_t)gr * 256 + k0 + s * 8;
                    float4 x0 = *(const float4*)xp;
                    float4 x1 = *(const float4*)(xp + 4);
                    B16 o;
                    o.b[0] = (__bf16)x0.x; o.b[1] = (__bf16)x0.y; o.b[2] = (__bf16)x0.z; o.b[3] = (__bf16)x0.w;
                    o.b[4] = (__bf16)x1.x; o.b[5] = (__bf16)x1.y; o.b[6] = (__bf16)x1.z; o.b[7] = (__bf16)x1.w;
                    va = o.u;
                }
            } else { va.x = va.y = va.z = va.w = 0u; }
            As4[r * 4 + sp] = va;
            Bs4[r * 4 + sp] = *(const uint4*)(WT + (size_t)(col0 + r) * 256 + k0 + s * 8);
        }
        __syncthreads();
        B16 af[4], bfr[4];
#pragma unroll
        for (int i = 0; i < 4; ++i) {
            const int ra = wm * 64 + i * 16 + lr;
            af[i].u = As4[ra * 4 + (ks ^ ((ra >> 1) & 3))];
            const int rb = wn * 64 + i * 16 + lr;
            bfr[i].u = Bs4[rb * 4 + (ks ^ ((rb >> 1) & 3))];
        }
#pragma unroll
        for (int i = 0; i < 4; ++i)
#pragma unroll
            for (int jn = 0; jn < 4; ++jn)
                acc[i][jn] = __builtin_amdgcn_mfma_f32_16x16x32_bf16(af[i].s, bfr[jn].s, acc[i][jn], 0, 0, 0);
        __syncthreads();
    }
    const int lq = l >> 4;
#pragma unroll
    for (int i = 0; i < 4; ++i) {
        const int rbase = row0 + wm * 64 + i * 16 + lq * 4;
#pragma unroll
        for (int jn = 0; jn < 4; ++jn) {
            const int col = col0 + wn * 64 + jn * 16 + lr;
            const float bv = bias[col];
#pragma unroll
            for (int r = 0; r < 4; ++r) {
                const int grow = rbase + r;
                if (grow < M) {
                    const float v = acc[i][jn][r] + bv;
                    if (OUT_BF16) ((bf16_t*)Yv)[(size_t)grow * ldY + col] = (bf16_t)v;
                    else          ((float*)Yv)[(size_t)grow * ldY + col] = v;
                }
            }
        }
    }
}

// ---------- per-node online-softmax aggregation (merged node types, bf16 out) ----------
__device__ __forceinline__ float4 ldb4(const bf16_t* p) {
    bf16x4 v = *(const bf16x4*)p;
    return make_float4((float)v[0], (float)v[1], (float)v[2], (float)v[3]);
}

__device__ __forceinline__ void aggr_list(
    const bf16_t* __restrict__ K, const bf16_t* __restrict__ V, int ld,
    const int* __restrict__ rp, const int* __restrict__ srcs,
    float scaleH, int node, int lane, const float4& q, float4& accOut)
{
    const int rs = rp[node], re = rp[node + 1];
    if (rs == re) return;
    float m = NEG_INF, den = 0.f;
    float4 acc = make_float4(0.f, 0.f, 0.f, 0.f);
    int sNext = srcs[rs];
    for (int i = rs; i < re; ++i) {
        const int s = sNext;
        if (i + 1 < re) sNext = srcs[i + 1];
        const float4 k4 = ldb4(K + (size_t)s * ld + lane * 4);
        const float4 v4 = ldb4(V + (size_t)s * ld + lane * 4);
        float part = q.x * k4.x + q.y * k4.y + q.z * k4.z + q.w * k4.w;
        part += __shfl_xor(part, 1, 64);
        part += __shfl_xor(part, 2, 64);
        part += __shfl_xor(part, 4, 64);
        const float score = part * scaleH;
        const float nm = fmaxf(m, score);
        const float r = __expf(m - nm);
        const float p = __expf(score - nm);
        den = den * r + p;
        acc.x = acc.x * r + v4.x * p;
        acc.y = acc.y * r + v4.y * p;
        acc.z = acc.z * r + v4.z * p;
        acc.w = acc.w * r + v4.w * p;
        m = nm;
    }
    const float inv = 1.f / den;
    accOut.x += acc.x * inv;
    accOut.y += acc.y * inv;
    accOut.z += acc.z * inv;
    accOut.w += acc.w * inv;
}

__global__ __launch_bounds__(256) void node_aggr(
    const bf16_t* __restrict__ Qp, const bf16_t* __restrict__ Qa,
    const bf16_t* __restrict__ Yhp, const bf16_t* __restrict__ Yha,
    const int* __restrict__ rp0, const int* __restrict__ sr0,
    const int* __restrict__ rp1, const int* __restrict__ sr1,
    const int* __restrict__ rp2, const int* __restrict__ sr2,
    const float* __restrict__ rel_pri, bf16_t* __restrict__ MUb)
{
    int gid = blockIdx.x * 256 + threadIdx.x;
    int node = gid >> 6;
    if (node >= NP + NA) return;
    int lane = gid & 63;
    int h = lane >> 3;
    float4 acc = make_float4(0.f, 0.f, 0.f, 0.f);
    float scale;
    if (node < NP) {
        const float4 q = ldb4(Qp + (size_t)node * 256 + lane * 4);
        aggr_list(Yha, Yha + 256, 512,  rp0, sr0, rel_pri[h]      * INV_SQRT_DK, node, lane, q, acc);
        aggr_list(Yhp, Yhp + 256, 1024, rp1, sr1, rel_pri[8 + h]  * INV_SQRT_DK, node, lane, q, acc);
        scale = 0.5f;
    } else {
        const int n2 = node - NP;
        const float4 q = ldb4(Qa + (size_t)n2 * 256 + lane * 4);
        aggr_list(Yhp + 512, Yhp + 768, 1024, rp2, sr2, rel_pri[16 + h] * INV_SQRT_DK, n2, lane, q, acc);
        scale = 1.f;
    }
    bf16x4 o;
    o[0] = (__bf16)(acc.x * scale); o[1] = (__bf16)(acc.y * scale);
    o[2] = (__bf16)(acc.z * scale); o[3] = (__bf16)(acc.w * scale);
    *(bf16x4*)(MUb + (size_t)node * 256 + lane * 4) = o;
}

// ---------- skip-blend + LayerNorm (merged node types, in-place on d_out) ----------
__global__ __launch_bounds__(256) void out_ln(
    const float* __restrict__ O, const float* __restrict__ Tp, const float* __restrict__ Ta,
    const float* __restrict__ skip, const float* __restrict__ lns,
    const float* __restrict__ lnb, float* __restrict__ out)
{
    int gid = blockIdx.x * 256 + threadIdx.x;
    int row = gid >> 6;
    if (row >= NP + NA) return;
    int lane = gid & 63;
    const int nt = row < NP ? 0 : 1;
    const float* T = (nt == 0) ? (Tp + (size_t)row * 256) : (Ta + (size_t)(row - NP) * 256);
    float alpha = 1.f / (1.f + expf(-skip[nt]));
    float beta = 1.f - alpha;
    const float4 o4 = *(const float4*)(O + (size_t)row * 256 + lane * 4);
    const float4 t4 = *(const float4*)(T + lane * 4);
    float v[4] = { o4.x * alpha + t4.x * beta, o4.y * alpha + t4.y * beta,
                   o4.z * alpha + t4.z * beta, o4.w * alpha + t4.w * beta };
    float s = v[0] + v[1] + v[2] + v[3];
#pragma unroll
    for (int mlane = 32; mlane >= 1; mlane >>= 1) s += __shfl_xor(s, mlane, 64);
    float mean = s * (1.f / 256.f);
    float sq = 0.f;
#pragma unroll
    for (int j = 0; j < 4; ++j) { float dd = v[j] - mean; sq += dd * dd; }
#pragma unroll
    for (int mlane = 32; mlane >= 1; mlane >>= 1) sq += __shfl_xor(sq, mlane, 64);
    float rstd = rsqrtf(sq * (1.f / 256.f) + 1e-5f);
    int c = lane * 4;
    const float* ls = lns + nt * 256 + c;
    const float* lb = lnb + nt * 256 + c;
    float4 r;
    r.x = (v[0] - mean) * rstd * ls[0] + lb[0];
    r.y = (v[1] - mean) * rstd * ls[1] + lb[1];
    r.z = (v[2] - mean) * rstd * ls[2] + lb[2];
    r.w = (v[3] - mean) * rstd * ls[3] + lb[3];
    *(float4*)(out + (size_t)row * 256 + c) = r;
}

extern "C" void kernel_launch(void* const* d_in, const int* in_sizes, int n_in,
                              void* d_out, int out_size, void* d_ws, size_t ws_size,
                              hipStream_t stream) {
    const float* h_paper  = (const float*)d_in[0];
    const float* h_author = (const float*)d_in[1];
    const float* t_paper  = (const float*)d_in[2];
    const float* t_author = (const float*)d_in[3];
    const float* k_w = (const float*)d_in[4];
    const float* k_b = (const float*)d_in[5];
    const float* q_w = (const float*)d_in[6];
    const float* q_b = (const float*)d_in[7];
    const float* v_w = (const float*)d_in[8];
    const float* v_b = (const float*)d_in[9];
    const float* a_w = (const float*)d_in[10];
    const float* a_b = (const float*)d_in[11];
    const float* rel_pri = (const float*)d_in[12];
    const float* rel_att = (const float*)d_in[13];
    const float* rel_msg = (const float*)d_in[14];
    const float* skip = (const float*)d_in[15];
    const float* ln_s = (const float*)d_in[16];
    const float* ln_b = (const float*)d_in[17];
    const int* src0 = (const int*)d_in[18];
    const int* dst0 = (const int*)d_in[19];
    const int* src1 = (const int*)d_in[20];
    const int* dst1 = (const int*)d_in[21];
    const int* src2 = (const int*)d_in[22];
    const int* dst2 = (const int*)d_in[23];

    // ---- workspace layout ----
    char* base = (char*)d_ws;
    size_t off = 0;
    auto alloc = [&](size_t bytes) { char* p = base + off; off += (bytes + 255) & ~(size_t)255; return p; };
    bf16_t* Yhp  = (bf16_t*)alloc((size_t)NP * 1024 * 2);  // K1|V1|K2|V2
    bf16_t* Yha  = (bf16_t*)alloc((size_t)NA * 512 * 2);   // K0|V0
    bf16_t* Qp   = (bf16_t*)alloc((size_t)NP * 256 * 2);
    bf16_t* Qa   = (bf16_t*)alloc((size_t)NA * 256 * 2);
    bf16_t* MUb  = (bf16_t*)alloc((size_t)(NP + NA) * 256 * 2);
    bf16_t* WT_hp = (bf16_t*)alloc(1024 * 256 * 2);
    bf16_t* WT_ha = (bf16_t*)alloc(512 * 256 * 2);
    bf16_t* WT_q0 = (bf16_t*)alloc(256 * 256 * 2);
    bf16_t* WT_q1 = (bf16_t*)alloc(256 * 256 * 2);
    bf16_t* WT_a0 = (bf16_t*)alloc(256 * 256 * 2);
    bf16_t* WT_a1 = (bf16_t*)alloc(256 * 256 * 2);
    float* Bhp = (float*)alloc(1024 * 4);
    float* Bha = (float*)alloc(512 * 4);
    int* cnt0 = (int*)alloc(100000 * 4);  // cnt0,cnt1,cnt2,run0,run1,run2 contiguous
    int* cnt1 = cnt0 + 20000;
    int* cnt2 = cnt1 + 20000;
    int* run0 = cnt2 + 10000;
    int* run1 = run0 + 20000;
    int* run2 = run1 + 20000;
    int* rp0 = (int*)alloc(20001 * 4);
    int* rp1 = (int*)alloc(20001 * 4);
    int* rp2 = (int*)alloc(10001 * 4);
    int* sr0 = (int*)alloc(100000 * 4);
    int* sr1 = (int*)alloc(100000 * 4);
    int* sr2 = (int*)alloc(100000 * 4);

    const int gE = (NEDGE + 255) / 256;

    // ---- CSR build ----
    fill_u32<<<(100000 + 255) / 256, 256, 0, stream>>>((unsigned*)cnt0, 0u, 100000);
    count3<<<dim3(gE, 3), 256, 0, stream>>>(dst0, dst1, dst2, cnt0, cnt1, cnt2, NEDGE);
    scan3<<<3, 256, 0, stream>>>(cnt0, cnt1, cnt2, rp0, rp1, rp2);
    scatter3<<<dim3(gE, 3), 256, 0, stream>>>(src0, dst0, src1, dst1, src2, dst2,
                                              rp0, rp1, rp2, run0, run1, run2,
                                              sr0, sr1, sr2, NEDGE);

    // ---- weight prep (all 10 jobs in one launch) ----
    prep_weights<<<dim3(256, 10), 256, 0, stream>>>(k_w, k_b, v_w, v_b, q_w, a_w,
                                                    rel_att, rel_msg,
                                                    WT_hp, Bhp, WT_ha, Bha,
                                                    WT_q0, WT_q1, WT_a0, WT_a1);

    // ---- projections (fp32 in, bf16 out) ----
    gemm_mfma<0, 1><<<dim3(157 + 79, 8), 256, 0, stream>>>(
        h_paper, WT_hp, Bhp, Yhp, NP, 157, 1024,
        h_author, WT_ha, Bha, Yha, NA, 512);
    gemm_mfma<0, 1><<<dim3(157 + 79, 2), 256, 0, stream>>>(
        t_paper, WT_q0, q_b, Qp, NP, 157, 256,
        t_author, WT_q1, q_b + 256, Qa, NA, 256);

    // ---- per-node online softmax + aggregation (bf16 out, 0.5 folded for papers) ----
    node_aggr<<<((NP + NA) * 64 + 255) / 256, 256, 0, stream>>>(
        Qp, Qa, Yhp, Yha, rp0, sr0, rp1, sr1, rp2, sr2, rel_pri, MUb);

    // ---- output linear (bf16 in, fp32 out) ----
    float* out = (float*)d_out;
    gemm_mfma<1, 0><<<dim3(157 + 79, 2), 256, 0, stream>>>(
        MUb, WT_a0, a_b, out, NP, 157, 256,
        MUb + (size_t)NP * 256, WT_a1, a_b + 256, out + (size_t)NP * 256, NA, 256);

    // ---- skip + LayerNorm (in-place) ----
    out_ln<<<((NP + NA) * 64 + 255) / 256, 256, 0, stream>>>(out, t_paper, t_author,
                                                             skip, ln_s, ln_b, out);
}